// Round 6
// baseline (1851.145 us; speedup 1.0000x reference)
//
#include <hip/hip_runtime.h>
#include <stdint.h>

// SRTKAN v7:
//  - gemm role: W half-tile [64 x K] RESIDENT in LDS (frags hoisted to regs), A
//    streamed ring-2 across 32 M-tiles -> one continuous 64/128-iteration pipeline
//    (sync -> stage-next async -> compute). Deep loop = steady-state staging (the
//    m97 property my short-K gemms lacked). 96+96 gemm blocks + 64 seq = grid 256
//    = exactly 1 block/CU, ONE round, all roles resident from t=0.
//  - seq role unchanged (58us/chunk proven). tail v2 unchanged.

constexpr int B_  = 512;
constexpr int T_  = 512;
constexpr int IN_ = 128;
constexpr int H_  = 256;
constexpr int GR_ = 32;                   // batch groups (fallback path)
constexpr int PL_ = GR_ * 2 * 4096;       // elements per parity plane (fallback path)
constexpr int TCp = 64;                   // pipeline chunk (T steps)
constexpr int NCp = 8;                    // chunks

typedef __attribute__((ext_vector_type(8))) short bf16x8;
typedef __attribute__((ext_vector_type(4))) float f32x4;

#define MFMA16(a, b, c) __builtin_amdgcn_mfma_f32_16x16x32_bf16((a), (b), (c), 0, 0, 0)

__device__ __forceinline__ float bf2f(unsigned short u){
    union { unsigned int i; float f; } v; v.i = ((unsigned int)u) << 16; return v.f;
}
__device__ __forceinline__ unsigned short f2bf(float f){
    union { float f; unsigned int i; } v; v.f = f;
    return (unsigned short)((v.i + 0x7FFFu + ((v.i >> 16) & 1u)) >> 16); // RNE
}
__device__ __forceinline__ unsigned int cvtpk(float a, float b){
    unsigned int r;
    asm("v_cvt_pk_bf16_f32 %0, %1, %2" : "=v"(r) : "v"(a), "v"(b));
    return r;
}
__device__ __forceinline__ unsigned long long pk4(float a, float b, float c, float d){
    const unsigned int lo = cvtpk(a, b), hi = cvtpk(c, d);
    return (unsigned long long)lo | ((unsigned long long)hi << 32);
}
__device__ __forceinline__ float sig_(float x){
    return __builtin_amdgcn_rcpf(1.0f + __expf(-x));
}
__device__ __forceinline__ float tanh_(float x){
    return 1.0f - 2.0f * __builtin_amdgcn_rcpf(1.0f + __expf(2.0f * x));
}
__device__ __forceinline__ bf16x8 ldb8g(const unsigned short* p){ return *(const bf16x8*)p; }

union U64x2 { unsigned long long q[2]; bf16x8 v; };

__device__ __forceinline__ void gl2lds16(const void* g, void* l){
    __builtin_amdgcn_global_load_lds(
        (const __attribute__((address_space(1))) unsigned int*)g,
        (__attribute__((address_space(3))) unsigned int*)l, 16, 0, 0);
}

// ---------------------------------------------------------------------------
// dtype detect
// ---------------------------------------------------------------------------
__global__ void srt_detect(const unsigned int* __restrict__ xw, unsigned int* __restrict__ flag){
    int cnt = 0;
    for (int i = threadIdx.x; i < 1024; i += 64){
        const unsigned int lo = xw[i] & 0xFFFFu;
        const int e = (int)((lo >> 7) & 0xFFu);
        if (e >= 100 && e <= 140) cnt++;
    }
    #pragma unroll
    for (int o = 32; o > 0; o >>= 1) cnt += __shfl_down(cnt, o);
    if (threadIdx.x == 0) *flag = (cnt > 614) ? 1u : 0u;   // 1 = bf16 inputs
}

// ---------------------------------------------------------------------------
// stage weights as bf16
// ---------------------------------------------------------------------------
struct ConvTab { const void* src[26]; int n[26]; int off[26]; };

__global__ __launch_bounds__(256) void srt_conv(ConvTab ct, unsigned short* __restrict__ wb,
                                                const unsigned int* __restrict__ flag){
    const bool isb = (*flag != 0);
    const int gsz = gridDim.x * blockDim.x;
    const int gid = blockIdx.x * blockDim.x + threadIdx.x;
    for (int j = 0; j < 26; ++j){
        const int n = ct.n[j];
        unsigned short* o = wb + ct.off[j];
        if (isb){
            const unsigned short* s = (const unsigned short*)ct.src[j];
            for (int i = gid; i < n; i += gsz) o[i] = s[i];
        } else {
            const float* s = (const float*)ct.src[j];
            for (int i = gid; i < n; i += gsz) o[i] = f2bf(s[i]);
        }
    }
}

// ---------------------------------------------------------------------------
// prep: zero states/counters; fold biases: bias[n] = bih[n] + (n<512 ? bhh[n] : 0)
// ---------------------------------------------------------------------------
__global__ __launch_bounds__(256) void srt_prep(
    float* __restrict__ h0s, float* __restrict__ h1s,
    float* __restrict__ bias0, float* __restrict__ bias1,
    const unsigned short* __restrict__ b0ih, const unsigned short* __restrict__ b0hh,
    const unsigned short* __restrict__ b1ih, const unsigned short* __restrict__ b1hh,
    unsigned int* __restrict__ seq)
{
    const int gid = blockIdx.x * blockDim.x + threadIdx.x;  // grid 512*256
    h0s[gid] = 0.f;
    h1s[gid] = 0.f;
    if (gid < 768){
        bias0[gid] = bf2f(b0ih[gid]) + (gid < 512 ? bf2f(b0hh[gid]) : 0.f);
        bias1[gid] = bf2f(b1ih[gid]) + (gid < 512 ? bf2f(b1hh[gid]) : 0.f);
    }
    if (gid < 1024) seq[gid] = 0u;
}

// ---------------------------------------------------------------------------
// seq role: one GRU layer, TC steps, 16 batch rows (group bg), 512 threads.
// (unchanged — measured 58us/chunk)
// shm carve: wnL[32768] | hbuf[2*4096] | gib[2*12288]
// ---------------------------------------------------------------------------
__device__ void seq_dev(unsigned short* shm,
    const unsigned short* __restrict__ gi,
    const unsigned short* __restrict__ whh,
    const unsigned short* __restrict__ bhh,
    float* __restrict__ hstate,
    unsigned short* __restrict__ h_all,
    const int TC, const int bg)
{
    unsigned short* wnL   = shm;
    unsigned short* hbufB = shm + 32768;
    unsigned short* gibB  = shm + 32768 + 8192;

    const int tid  = threadIdx.x;
    const int lane = tid & 63;
    const int wv   = tid >> 6;
    const int l15  = lane & 15;
    const int quad = lane >> 4;
    const int m0   = bg * 16;
    const int swz  = (l15 & 7) << 4;

    bf16x8 wr[5][8];
    #pragma unroll
    for (int fi = 0; fi < 6; ++fi){
        const int u = fi >> 1, ii = fi & 1;
        const unsigned short* wp =
            whh + (size_t)(u * 256 + wv * 32 + ii * 16 + l15) * 256 + quad * 8;
        if (fi < 5){
            #pragma unroll
            for (int kc = 0; kc < 8; ++kc) wr[fi][kc] = ldb8g(wp + kc * 32);
        } else {
            #pragma unroll
            for (int kc = 0; kc < 8; ++kc)
                *(bf16x8*)&wnL[((wv * 8 + kc) << 9) + lane * 8] = ldb8g(wp + kc * 32);
        }
    }

    f32x4 bn0[2];
    #pragma unroll
    for (int ii = 0; ii < 2; ++ii)
        #pragma unroll
        for (int j = 0; j < 4; ++j)
            bn0[ii][j] = bf2f(bhh[512 + wv * 32 + ii * 16 + quad * 4 + j]);

    f32x4 hr[2];
    #pragma unroll
    for (int ii = 0; ii < 2; ++ii)
        hr[ii] = *(const f32x4*)&hstate[(size_t)(m0 + l15) * 256 + wv * 32 + ii * 16 + quad * 4];

    const unsigned short* gpp[3]; int gdl[3];
    #pragma unroll
    for (int i = 0; i < 3; ++i){
        const int g_  = i * 512 + tid;
        const int row = g_ / 96;
        const int cg  = g_ - row * 96;
        gpp[i] = gi + ((size_t)m0 + row) * 768 + ((cg ^ (row & 7)) << 3);
        gdl[i] = g_ * 8;
    }

    #pragma unroll
    for (int ii = 0; ii < 2; ++ii){
        const unsigned long long pk = pk4(hr[ii][0], hr[ii][1], hr[ii][2], hr[ii][3]);
        *(unsigned long long*)((char*)hbufB + l15 * 512 +
            ((wv * 64 + ii * 32 + quad * 8) ^ swz)) = pk;
    }
    #pragma unroll
    for (int i = 0; i < 3; ++i) gl2lds16(gpp[i], &gibB[gdl[i]]);
    __syncthreads();

    #pragma unroll 1
    for (int t = 0; t < TC; ++t){
        const int par = t & 1;
        unsigned short* hb_cur = hbufB + par * 4096;
        unsigned short* hb_nxt = hbufB + (par ^ 1) * 4096;
        unsigned short* gb_cur = gibB + par * 12288;
        unsigned short* gb_nxt = gibB + (par ^ 1) * 12288;

        if (t + 1 < TC){
            const size_t toff = (size_t)(t + 1) * (512 * 768);
            #pragma unroll
            for (int i = 0; i < 3; ++i) gl2lds16(gpp[i] + toff, &gb_nxt[gdl[i]]);
        }

        f32x4 aR0 = {0,0,0,0}, aR1 = {0,0,0,0}, aZ0 = {0,0,0,0}, aZ1 = {0,0,0,0};
        f32x4 aN0 = bn0[0], aN1 = bn0[1];
        __builtin_amdgcn_s_setprio(1);
        #pragma unroll
        for (int kc = 0; kc < 8; ++kc){
            const bf16x8 hb = *(const bf16x8*)((const char*)hb_cur +
                l15 * 512 + ((kc * 64 + quad * 16) ^ swz));
            const bf16x8 w5 = *(const bf16x8*)&wnL[((wv * 8 + kc) << 9) + lane * 8];
            aR0 = MFMA16(wr[0][kc], hb, aR0);
            aR1 = MFMA16(wr[1][kc], hb, aR1);
            aZ0 = MFMA16(wr[2][kc], hb, aZ0);
            aZ1 = MFMA16(wr[3][kc], hb, aZ1);
            aN0 = MFMA16(wr[4][kc], hb, aN0);
            aN1 = MFMA16(w5,        hb, aN1);
        }
        __builtin_amdgcn_s_setprio(0);

        const char* gbase = (const char*)gb_cur + l15 * 1536;
        #pragma unroll
        for (int ii = 0; ii < 2; ++ii){
            const int cb = wv * 64 + ii * 32 + quad * 8;
            const unsigned long long qr = *(const unsigned long long*)(gbase + ((       cb) ^ swz));
            const unsigned long long qz = *(const unsigned long long*)(gbase + ((512  + cb) ^ swz));
            const unsigned long long qn = *(const unsigned long long*)(gbase + ((1024 + cb) ^ swz));
            const f32x4 aR = ii ? aR1 : aR0;
            const f32x4 aZ = ii ? aZ1 : aZ0;
            const f32x4 aN = ii ? aN1 : aN0;
            #pragma unroll
            for (int j = 0; j < 4; ++j){
                const float rr = sig_(aR[j] + bf2f((unsigned short)(qr >> (16 * j))));
                const float zz = sig_(aZ[j] + bf2f((unsigned short)(qz >> (16 * j))));
                const float nn = tanh_(bf2f((unsigned short)(qn >> (16 * j))) + rr * aN[j]);
                hr[ii][j] = (1.0f - zz) * nn + zz * hr[ii][j];
            }
        }

        #pragma unroll
        for (int ii = 0; ii < 2; ++ii){
            const unsigned long long pk = pk4(hr[ii][0], hr[ii][1], hr[ii][2], hr[ii][3]);
            *(unsigned long long*)((char*)hb_nxt + l15 * 512 +
                ((wv * 64 + ii * 32 + quad * 8) ^ swz)) = pk;
            if (h_all)
                *(unsigned long long*)(h_all + ((size_t)t * 512 + m0 + l15) * 256 +
                    wv * 32 + ii * 16 + quad * 4) = pk;
        }

        __syncthreads();
    }

    #pragma unroll
    for (int ii = 0; ii < 2; ++ii)
        *(f32x4*)&hstate[(size_t)(m0 + l15) * 256 + wv * 32 + ii * 16 + quad * 4] = hr[ii];
}

// ---------------------------------------------------------------------------
// gemm role v3 (deep-loop): block owns feat half-tile nb (64 cols of 768) and
// M-group mg (4096 rows = 32 M-tiles of 128). W[64xK] resident in LDS, frags
// hoisted to regs. A chunks [128x64] ring-2, staged async AFTER each barrier so
// loads overlap current compute (steady-state from iter 1; 64/128 iters total).
// Per iter/wave: 4 ds_read_b128 + 8 MFMA. Store D[feat][row] packed b64.
// shm carve: Wt[64*K] | Ab[2*8192].
// ---------------------------------------------------------------------------
template<int K, bool XS>
__device__ void gemm_dev(unsigned short* shm, const void* Asrc, const bool isb,
                         const int t0, const unsigned short* __restrict__ W,
                         const float* __restrict__ bias,
                         unsigned short* __restrict__ C,
                         const int nb, const int mg)
{
    unsigned short* Wt = shm;                   // 64*K shorts (16/32 KB)
    unsigned short* Ab = shm + 64 * K;          // 2 * 8192 shorts (32 KB)

    const int tid = threadIdx.x;                // 0..511
    const int lane = tid & 63, wv = tid >> 6;
    const int l15 = lane & 15, quad = lane >> 4;
    const int fh = wv & 1, mq = wv >> 1;        // feat-half(32), M-quarter(32 rows)
    constexpr int NK  = K / 64;                 // A chunks per M-tile
    constexpr int GW  = K / 8;                  // W granules per row
    constexpr int WG  = 64 * GW / 512;          // W granules per thread
    constexpr int NIT = 32 * NK;

    // ---- stage resident W tile (source-XOR by row)
    #pragma unroll
    for (int i = 0; i < WG; ++i){
        const int g_ = i * 512 + tid;
        const int row = g_ / GW, cg = g_ % GW;
        gl2lds16(W + (size_t)(nb * 64 + row) * K + ((cg ^ (row & 7)) << 3), &Wt[g_ * 8]);
    }

    float bs[2][4];
    #pragma unroll
    for (int ni = 0; ni < 2; ++ni)
        #pragma unroll
        for (int j = 0; j < 4; ++j)
            bs[ni][j] = bias[nb * 64 + fh * 32 + ni * 16 + quad * 4 + j];

    // ---- A chunk stager: iter it -> M-tile it/NK, k-chunk it%NK, buf it&1
    auto stageA = [&](int it){
        const int mt = it / NK, kk = it % NK;
        unsigned short* dst = Ab + (it & 1) * 8192;
        #pragma unroll
        for (int i = 0; i < 2; ++i){
            const int g_ = i * 512 + tid;
            const int row = g_ >> 3, cg = g_ & 7;
            const int r = mg * 4096 + mt * 128 + row;
            if (XS){
                const int b = r & 511, tt = r >> 9;
                const size_t s0 = ((size_t)b * 512 + (t0 + tt)) * 128 + kk * 64;
                if (isb){
                    gl2lds16((const unsigned short*)Asrc + s0 + ((cg ^ (row & 7)) << 3),
                             &dst[g_ * 8]);
                } else {
                    const float* p = (const float*)Asrc + s0 + cg * 8;
                    const float4 f0 = *(const float4*)p;
                    const float4 f1 = *(const float4*)(p + 4);
                    uint4 u;
                    u.x = cvtpk(f0.x, f0.y); u.y = cvtpk(f0.z, f0.w);
                    u.z = cvtpk(f1.x, f1.y); u.w = cvtpk(f1.z, f1.w);
                    *(uint4*)&dst[(row * 8 + (cg ^ (row & 7))) * 8] = u;
                }
            } else {
                gl2lds16((const unsigned short*)Asrc + (size_t)r * K + kk * 64 +
                         ((cg ^ (row & 7)) << 3), &dst[g_ * 8]);
            }
        }
    };

    stageA(0);
    __syncthreads();     // W tile + A chunk 0 complete

    // ---- hoist W fragments: wf[ni][kk*2+kc]
    bf16x8 wf[2][2 * NK];
    #pragma unroll
    for (int ni = 0; ni < 2; ++ni)
        #pragma unroll
        for (int k2 = 0; k2 < 2 * NK; ++k2){
            const int rf = fh * 32 + ni * 16 + l15;
            wf[ni][k2] = *(const bf16x8*)((const char*)Wt +
                rf * (2 * K) + (((k2 * 4 + quad) ^ (rf & 7)) << 4));
        }

    // ---- main deep loop
    #pragma unroll 1
    for (int mt = 0; mt < 32; ++mt){
        f32x4 acc[2][2];
        #pragma unroll
        for (int ni = 0; ni < 2; ++ni){
            acc[ni][0] = (f32x4){0,0,0,0};
            acc[ni][1] = (f32x4){0,0,0,0};
        }

        #pragma unroll
        for (int kk = 0; kk < NK; ++kk){
            const int it = mt * NK + kk;
            if (it) __syncthreads();          // buf(it&1) loads complete; other buf free
            if (it + 1 < NIT) stageA(it + 1); // in flight during compute, drained next barrier

            const char* ab = (const char*)(Ab + (it & 1) * 8192);
            #pragma unroll
            for (int kc = 0; kc < 2; ++kc){
                bf16x8 af[2];
                #pragma unroll
                for (int mi = 0; mi < 2; ++mi){
                    const int ra = mq * 32 + mi * 16 + l15;
                    af[mi] = *(const bf16x8*)(ab + ra * 128 +
                              (((kc * 4 + quad) ^ (ra & 7)) << 4));
                }
                #pragma unroll
                for (int ni = 0; ni < 2; ++ni)
                    #pragma unroll
                    for (int mi = 0; mi < 2; ++mi)
                        acc[ni][mi] = MFMA16(wf[ni][kk * 2 + kc], af[mi], acc[ni][mi]);
            }
        }

        // store M-tile: D[m=feat quad*4+j][n=row l15] -> b64 of 4 feats
        #pragma unroll
        for (int ni = 0; ni < 2; ++ni)
            #pragma unroll
            for (int mi = 0; mi < 2; ++mi){
                const unsigned int lo = cvtpk(acc[ni][mi][0] + bs[ni][0],
                                              acc[ni][mi][1] + bs[ni][1]);
                const unsigned int hi = cvtpk(acc[ni][mi][2] + bs[ni][2],
                                              acc[ni][mi][3] + bs[ni][3]);
                const int row = mg * 4096 + mt * 128 + mq * 32 + mi * 16 + l15;
                const int col = nb * 64 + fh * 32 + ni * 16 + quad * 4;
                uint2 st; st.x = lo; st.y = hi;
                *(uint2*)(C + (size_t)row * 768 + col) = st;
            }
    }
}

// ---------------------------------------------------------------------------
// phase kernel: grid = 256 (1 block/CU, one round). block = 512, 128KB LDS.
//  [0,32) seq0(p-1) | [32,64) seq1(p-3) | [64,160) gemmx(p) | [160,256) gemm1(p-2)
// gemm roles: 96 blocks = 12 nb x 8 mg.
// ---------------------------------------------------------------------------
struct PA {
    const void* xv;
    const unsigned int* flag;
    const unsigned short *w0ih, *w0hh, *b0hh, *w1ih, *w1hh, *b1hh;
    const float *bias0, *bias1;
    float *h0s, *h1s;
    unsigned short *gi0a, *gi0b, *haa, *hab, *gi1a, *gi1b;
    int p;
};

__global__ __launch_bounds__(512, 1) void srt_phase(PA a){
    __shared__ __align__(16) unsigned short shm[65536];   // 128 KB
    const int bid = blockIdx.x;
    const int p = a.p;

    if (bid < 32){
        const int c = p - 1; if (c < 0 || c >= NCp) return;
        seq_dev(shm, (c & 1) ? a.gi0b : a.gi0a, a.w0hh, a.b0hh, a.h0s,
                (c & 1) ? a.hab : a.haa, TCp, bid);
    } else if (bid < 64){
        const int c = p - 3; if (c < 0 || c >= NCp) return;
        seq_dev(shm, (c & 1) ? a.gi1b : a.gi1a, a.w1hh, a.b1hh, a.h1s,
                nullptr, TCp, bid - 32);
    } else if (bid < 160){
        const int c = p; if (c >= NCp) return;
        const bool isb = (*a.flag != 0);
        const int idx = bid - 64;
        gemm_dev<128, true>(shm, a.xv, isb, c * TCp, a.w0ih, a.bias0,
                            (c & 1) ? a.gi0b : a.gi0a, idx % 12, idx / 12);
    } else {
        const int c = p - 2; if (c < 0 || c >= NCp) return;
        const int idx = bid - 160;
        gemm_dev<256, false>(shm, (c & 1) ? a.hab : a.haa, true, 0, a.w1ih, a.bias1,
                             (c & 1) ? a.gi1b : a.gi1a, idx % 12, idx / 12);
    }
}

// ---------------------------------------------------------------------------
// OLD PATH (fallback when ws_size too small): persistent GRU with LLC exchange.
// ---------------------------------------------------------------------------
__global__ __launch_bounds__(256, 1) void srt_gru(
    const void* __restrict__ xv,
    const unsigned short* __restrict__ w0ih,
    const unsigned short* __restrict__ w0hh,
    const unsigned short* __restrict__ b0ih,
    const unsigned short* __restrict__ b0hh,
    const unsigned short* __restrict__ w1ih,
    const unsigned short* __restrict__ w1hh,
    const unsigned short* __restrict__ b1ih,
    const unsigned short* __restrict__ b1hh,
    float* __restrict__ s_out,
    const unsigned int* __restrict__ flagp,
    unsigned int* __restrict__ seq,
    unsigned short* __restrict__ hb)
{
    __shared__ __align__(16) unsigned short w0hhL[4 * 24 * 512];

    const bool isb = (*flagp != 0);
    const int tid  = threadIdx.x;
    const int lane = tid & 63;
    const int wv   = tid >> 6;
    const int l15  = lane & 15;
    const int quad = lane >> 4;
    const int q    = blockIdx.x >> 5;
    const int g    = blockIdx.x & 31;
    const int m0   = g * 16;
    const int c    = q * 64 + wv * 16 + l15;

    bf16x8 w0ihr[3][4];
    #pragma unroll
    for (int u = 0; u < 3; ++u)
        #pragma unroll
        for (int kc = 0; kc < 4; ++kc)
            w0ihr[u][kc] = ldb8g(w0ih + (u * 256 + c) * IN_ + kc * 32 + quad * 8);

    bf16x8 w1ihr[3][8], w1hhr[3][8];
    #pragma unroll
    for (int u = 0; u < 3; ++u)
        #pragma unroll
        for (int kc = 0; kc < 8; ++kc){
            w1ihr[u][kc] = ldb8g(w1ih + (u * 256 + c) * H_ + kc * 32 + quad * 8);
            w1hhr[u][kc] = ldb8g(w1hh + (u * 256 + c) * H_ + kc * 32 + quad * 8);
        }

    const int wl = wv * 12288 + lane * 8;
    #pragma unroll
    for (int u = 0; u < 3; ++u)
        #pragma unroll
        for (int kc = 0; kc < 8; ++kc){
            const bf16x8 f = ldb8g(w0hh + (u * 256 + c) * H_ + kc * 32 + quad * 8);
            *(bf16x8*)&w0hhL[wl + (u * 8 + kc) * 512] = f;
        }

    const float brz0a = bf2f(b0ih[c])       + bf2f(b0hh[c]);
    const float brz0b = bf2f(b0ih[256 + c]) + bf2f(b0hh[256 + c]);
    const float bni0v = bf2f(b0ih[512 + c]);
    const float bnh0v = bf2f(b0hh[512 + c]);
    const float brz1a = bf2f(b1ih[c])       + bf2f(b1hh[c]);
    const float brz1b = bf2f(b1ih[256 + c]) + bf2f(b1hh[256 + c]);
    const float bni1v = bf2f(b1ih[512 + c]);
    const float bnh1v = bf2f(b1hh[512 + c]);
    __syncthreads();

    float h0r[4] = {0.f, 0.f, 0.f, 0.f};
    float h1r[4] = {0.f, 0.f, 0.f, 0.f};

    const size_t xrow = (size_t)(m0 + l15) * (T_ * IN_) + quad * 8;
    const unsigned short* pxb = (const unsigned short*)xv + xrow;
    const float*          pxf = (const float*)xv + xrow;

    unsigned int* sq = seq + g * 32;
    const int wr_row[4] = {(quad * 4 + 0) * 256 + c, (quad * 4 + 1) * 256 + c,
                           (quad * 4 + 2) * 256 + c, (quad * 4 + 3) * 256 + c};

    const f32x4 z4 = {0.f, 0.f, 0.f, 0.f};
    bf16x8 h0A[8], h1A[8];
    #pragma unroll
    for (int kc = 0; kc < 8; ++kc){
        h0A[kc] = (bf16x8)(short)0;
        h1A[kc] = (bf16x8)(short)0;
    }

    #pragma unroll 1
    for (int t = 0; t < T_; ++t){
        const int par = t & 1;
        const unsigned int tgt = 4u * (unsigned)(t + 1);
        unsigned short* plane = hb + par * PL_ + g * (2 * 4096);

        #pragma unroll
        for (int j = 0; j < 4; ++j)
            __hip_atomic_store(&plane[4096 + wr_row[j]], f2bf(h1r[j]),
                               __ATOMIC_RELAXED, __HIP_MEMORY_SCOPE_AGENT);

        bf16x8 ax[4];
        if (isb){
            #pragma unroll
            for (int kc = 0; kc < 4; ++kc) ax[kc] = ldb8g(pxb + t * IN_ + kc * 32);
        } else {
            #pragma unroll
            for (int kc = 0; kc < 4; ++kc){
                const float* p = pxf + t * IN_ + kc * 32;
                const float4 f0 = *(const float4*)p;
                const float4 f1 = *(const float4*)(p + 4);
                bf16x8 a;
                a[0] = (short)f2bf(f0.x); a[1] = (short)f2bf(f0.y);
                a[2] = (short)f2bf(f0.z); a[3] = (short)f2bf(f0.w);
                a[4] = (short)f2bf(f1.x); a[5] = (short)f2bf(f1.y);
                a[6] = (short)f2bf(f1.z); a[7] = (short)f2bf(f1.w);
                ax[kc] = a;
            }
        }

        f32x4 Tr = z4, Tz = z4, Tni = z4, Tnh = z4;
        #pragma unroll
        for (int kc = 0; kc < 4; ++kc){
            Tr  = MFMA16(ax[kc], w0ihr[0][kc], Tr);
            Tz  = MFMA16(ax[kc], w0ihr[1][kc], Tz);
            Tni = MFMA16(ax[kc], w0ihr[2][kc], Tni);
        }
        #pragma unroll
        for (int kc = 0; kc < 8; ++kc){
            const bf16x8 a = h0A[kc];
            Tr  = MFMA16(a, *(const bf16x8*)&w0hhL[wl + (0 * 8 + kc) * 512], Tr);
            Tz  = MFMA16(a, *(const bf16x8*)&w0hhL[wl + (1 * 8 + kc) * 512], Tz);
            Tnh = MFMA16(a, *(const bf16x8*)&w0hhL[wl + (2 * 8 + kc) * 512], Tnh);
        }
        #pragma unroll
        for (int j = 0; j < 4; ++j){
            const float rr = sig_(Tr[j] + brz0a);
            const float zz = sig_(Tz[j] + brz0b);
            const float nn = tanh_(Tni[j] + bni0v + rr * (Tnh[j] + bnh0v));
            h0r[j] = (1.0f - zz) * nn + zz * h0r[j];
        }

        #pragma unroll
        for (int j = 0; j < 4; ++j)
            __hip_atomic_store(&plane[wr_row[j]], f2bf(h0r[j]),
                               __ATOMIC_RELAXED, __HIP_MEMORY_SCOPE_AGENT);

        __syncthreads();
        if (tid == 0)
            __hip_atomic_fetch_add(sq, 1u, __ATOMIC_RELAXED, __HIP_MEMORY_SCOPE_AGENT);
        if (lane == 0){
            while (__hip_atomic_load(sq, __ATOMIC_RELAXED, __HIP_MEMORY_SCOPE_AGENT) < tgt)
                __builtin_amdgcn_s_sleep(1);
        }
        __atomic_signal_fence(__ATOMIC_ACQ_REL);

        {
            const unsigned short* r0 = plane + l15 * 256 + quad * 8;
            #pragma unroll
            for (int kc = 0; kc < 8; ++kc){
                U64x2 u0, u1;
                u0.q[0] = __hip_atomic_load((const unsigned long long*)(r0 + kc * 32),
                                            __ATOMIC_RELAXED, __HIP_MEMORY_SCOPE_AGENT);
                u0.q[1] = __hip_atomic_load((const unsigned long long*)(r0 + kc * 32 + 4),
                                            __ATOMIC_RELAXED, __HIP_MEMORY_SCOPE_AGENT);
                u1.q[0] = __hip_atomic_load((const unsigned long long*)(r0 + 4096 + kc * 32),
                                            __ATOMIC_RELAXED, __HIP_MEMORY_SCOPE_AGENT);
                u1.q[1] = __hip_atomic_load((const unsigned long long*)(r0 + 4096 + kc * 32 + 4),
                                            __ATOMIC_RELAXED, __HIP_MEMORY_SCOPE_AGENT);
                h0A[kc] = u0.v;
                h1A[kc] = u1.v;
            }
        }

        Tr = z4; Tz = z4; Tni = z4; Tnh = z4;
        #pragma unroll
        for (int kc = 0; kc < 8; ++kc){
            const bf16x8 a0 = h0A[kc];
            const bf16x8 a1 = h1A[kc];
            Tr  = MFMA16(a0, w1ihr[0][kc], Tr);
            Tr  = MFMA16(a1, w1hhr[0][kc], Tr);
            Tz  = MFMA16(a0, w1ihr[1][kc], Tz);
            Tz  = MFMA16(a1, w1hhr[1][kc], Tz);
            Tni = MFMA16(a0, w1ihr[2][kc], Tni);
            Tnh = MFMA16(a1, w1hhr[2][kc], Tnh);
        }
        #pragma unroll
        for (int j = 0; j < 4; ++j){
            const float rr = sig_(Tr[j] + brz1a);
            const float zz = sig_(Tz[j] + brz1b);
            const float nn = tanh_(Tni[j] + bni1v + rr * (Tnh[j] + bnh1v));
            h1r[j] = (1.0f - zz) * nn + zz * h1r[j];
        }
    }

    #pragma unroll
    for (int j = 0; j < 4; ++j)
        s_out[(size_t)(m0 + quad * 4 + j) * H_ + c] = h1r[j];
}

// ---------------------------------------------------------------------------
// B-spline basis (uniform grid, GRID_SIZE=5, ORDER=3)
// ---------------------------------------------------------------------------
__device__ __forceinline__ float knot_(int p){ return (float)(p - 3) * 0.4f - 1.0f; }

__device__ __forceinline__ void bspline8(float xv, float* bb8){
    float bb[11];
    #pragma unroll
    for (int p = 0; p < 11; ++p)
        bb[p] = (xv >= knot_(p) && xv < knot_(p + 1)) ? 1.f : 0.f;
    #pragma unroll
    for (int k = 1; k <= 3; ++k){
        #pragma unroll
        for (int p = 0; p <= 10 - k; ++p){
            const float tp = knot_(p), tpk = knot_(p + k);
            const float tp1 = knot_(p + 1), tpk1 = knot_(p + k + 1);
            bb[p] = (xv - tp) / (tpk - tp) * bb[p] + (tpk1 - xv) / (tpk1 - tp1) * bb[p + 1];
        }
    }
    #pragma unroll
    for (int j = 0; j < 8; ++j) bb8[j] = bb[j];
}

// partial LSTM dots over k in [k0, k0+64) for 3 gates (i,g,o) of unit uu
__device__ __forceinline__ void lstm_part(const float* sxv, const unsigned short* w,
                                          int uu, int k0, float* out3){
    const unsigned short* wi = w + (size_t)uu * 256 + k0;
    const unsigned short* wg = w + (size_t)(256 + uu) * 256 + k0;
    const unsigned short* wo = w + (size_t)(384 + uu) * 256 + k0;
    float ai = 0.f, ag = 0.f, ao = 0.f;
    for (int k = 0; k < 64; k += 8){
        const bf16x8 vi = ldb8g(wi + k);
        const bf16x8 vg = ldb8g(wg + k);
        const bf16x8 vo = ldb8g(wo + k);
        #pragma unroll
        for (int j = 0; j < 8; ++j){
            const float s = sxv[k0 + k + j];
            ai += bf2f((unsigned short)vi[j]) * s;
            ag += bf2f((unsigned short)vg[j]) * s;
            ao += bf2f((unsigned short)vo[j]) * s;
        }
    }
    out3[0] = ai; out3[1] = ag; out3[2] = ao;
}

// ---------------------------------------------------------------------------
// Fused tail v2: 1024 threads, 4-way k-split LSTMs + 16-way KAN splits.
// ---------------------------------------------------------------------------
__global__ __launch_bounds__(1024) void srt_tail(
    const float* __restrict__ in,
    const unsigned short* __restrict__ w0f, const unsigned short* __restrict__ bi0f,
    const unsigned short* __restrict__ bh0f,
    const unsigned short* __restrict__ w0r, const unsigned short* __restrict__ bi0r,
    const unsigned short* __restrict__ bh0r,
    const unsigned short* __restrict__ w1f, const unsigned short* __restrict__ bi1f,
    const unsigned short* __restrict__ bh1f,
    const unsigned short* __restrict__ w1r, const unsigned short* __restrict__ bi1r,
    const unsigned short* __restrict__ bh1r,
    const unsigned short* __restrict__ k1b, const unsigned short* __restrict__ k1s,
    const unsigned short* __restrict__ k1c,
    const unsigned short* __restrict__ k2b, const unsigned short* __restrict__ k2s,
    const unsigned short* __restrict__ k2c,
    void* __restrict__ outp,
    const unsigned int* __restrict__ flagp)
{
    __shared__ float sx[256];
    __shared__ float sy[256];
    __shared__ float part[4][256][3];
    __shared__ float sil[256];
    __shared__ float spl[256][8];
    __shared__ float red16[64][16];
    __shared__ float sil2[64];
    __shared__ float spl2[64][8];
    __shared__ float red2[10][16];

    const int b = blockIdx.x, tid = threadIdx.x;
    const int qr = tid >> 8, sub = tid & 255;
    const int dir = sub >> 7, uu = sub & 127;

    if (tid < 256) sx[tid] = in[b * 256 + tid];
    __syncthreads();

    float p3[3];
    lstm_part(sx, dir ? w0r : w0f, uu, qr * 64, p3);
    part[qr][sub][0] = p3[0]; part[qr][sub][1] = p3[1]; part[qr][sub][2] = p3[2];
    __syncthreads();
    if (tid < 256){
        const unsigned short* bi = dir ? bi0r : bi0f;
        const unsigned short* bh = dir ? bh0r : bh0f;
        const float ai = part[0][sub][0] + part[1][sub][0] + part[2][sub][0] + part[3][sub][0];
        const float ag = part[0][sub][1] + part[1][sub][1] + part[2][sub][1] + part[3][sub][1];
        const float ao = part[0][sub][2] + part[1][sub][2] + part[2][sub][2] + part[3][sub][2];
        const float gi = ai + bf2f(bi[uu])       + bf2f(bh[uu]);
        const float gg = ag + bf2f(bi[256 + uu]) + bf2f(bh[256 + uu]);
        const float go = ao + bf2f(bi[384 + uu]) + bf2f(bh[384 + uu]);
        sy[sub] = sig_(go) * tanh_(sig_(gi) * tanh_(gg));
    }
    __syncthreads();

    lstm_part(sy, dir ? w1r : w1f, uu, qr * 64, p3);
    part[qr][sub][0] = p3[0]; part[qr][sub][1] = p3[1]; part[qr][sub][2] = p3[2];
    __syncthreads();
    if (tid < 256){
        const unsigned short* bi = dir ? bi1r : bi1f;
        const unsigned short* bh = dir ? bh1r : bh1f;
        const float ai = part[0][sub][0] + part[1][sub][0] + part[2][sub][0] + part[3][sub][0];
        const float ag = part[0][sub][1] + part[1][sub][1] + part[2][sub][1] + part[3][sub][1];
        const float ao = part[0][sub][2] + part[1][sub][2] + part[2][sub][2] + part[3][sub][2];
        const float gi = ai + bf2f(bi[uu])       + bf2f(bh[uu]);
        const float gg = ag + bf2f(bi[256 + uu]) + bf2f(bh[256 + uu]);
        const float go = ao + bf2f(bi[384 + uu]) + bf2f(bh[384 + uu]);
        const float o1v = sig_(go) * tanh_(sig_(gi) * tanh_(gg));
        sil[sub] = o1v * sig_(o1v);
        float bb[8];
        bspline8(o1v, bb);
        #pragma unroll
        for (int j = 0; j < 8; ++j) spl[sub][j] = bb[j];
    }
    __syncthreads();

    {
        const int o = tid >> 4, q16 = tid & 15;
        float acc = 0.f;
        for (int k = q16 * 16; k < q16 * 16 + 16; ++k){
            acc += sil[k] * bf2f(k1b[o * 256 + k]);
            float t = 0.f;
            #pragma unroll
            for (int j = 0; j < 8; ++j) t += spl[k][j] * bf2f(k1s[(o * 256 + k) * 8 + j]);
            acc += t * bf2f(k1c[o * 256 + k]);
        }
        red16[o][q16] = acc;
    }
    __syncthreads();
    if (tid < 64){
        float zv = 0.f;
        #pragma unroll
        for (int i = 0; i < 16; ++i) zv += red16[tid][i];
        sil2[tid] = zv * sig_(zv);
        float b2[8];
        bspline8(zv, b2);
        #pragma unroll
        for (int j = 0; j < 8; ++j) spl2[tid][j] = b2[j];
    }
    __syncthreads();

    if (tid < 160){
        const int o2 = tid >> 4, q = tid & 15;
        float a2 = 0.f;
        for (int k = q * 4; k < q * 4 + 4; ++k){
            a2 += sil2[k] * bf2f(k2b[o2 * 64 + k]);
            float t = 0.f;
            #pragma unroll
            for (int j = 0; j < 8; ++j) t += spl2[k][j] * bf2f(k2s[(o2 * 64 + k) * 8 + j]);
            a2 += t * bf2f(k2c[o2 * 64 + k]);
        }
        red2[o2][q] = a2;
    }
    __syncthreads();
    if (tid < 10){
        float a2 = 0.f;
        #pragma unroll
        for (int i = 0; i < 16; ++i) a2 += red2[tid][i];
        if (*flagp) ((unsigned short*)outp)[b * 10 + tid] = f2bf(a2);
        else        ((float*)outp)[b * 10 + tid] = a2;
    }
}

extern "C" void kernel_launch(void* const* d_in, const int* in_sizes, int n_in,
                              void* d_out, int out_size, void* d_ws, size_t ws_size,
                              hipStream_t stream)
{
    unsigned int* flag = (unsigned int*)d_ws;
    float* s = (float*)((char*)d_ws + 16);            // final h1 (fp32)
    unsigned short* wb = (unsigned short*)(s + 512 * 256);

    const int idxs[26] = {1,2,3,4,5,6,7,8, 9,11,12, 13,15,16, 17,19,20, 21,23,24,
                          25,26,27, 28,29,30};
    ConvTab ct;
    int off = 0;
    int offs[26];
    for (int j = 0; j < 26; ++j){
        ct.src[j] = d_in[idxs[j]];
        ct.n[j]   = in_sizes[idxs[j]];
        ct.off[j] = off;
        offs[j]   = off;
        off += in_sizes[idxs[j]];
    }
    uintptr_t p = (uintptr_t)(wb + off);
    p = (p + 255) & ~(uintptr_t)255;
    unsigned int* seq = (unsigned int*)p;                 // fallback counters
    unsigned short* hb = (unsigned short*)(seq + 1024);   // fallback exchange buf
    p = (uintptr_t)(hb + 2 * 32 * 2 * 4096);
    p = (p + 255) & ~(uintptr_t)255;
    float* h0s   = (float*)p;                             // 512*256 fp32 layer-0 state
    float* bias0 = h0s + 512 * 256;
    float* bias1 = bias0 + 768;
    p = (uintptr_t)(bias1 + 768);
    p = (p + 255) & ~(uintptr_t)255;
    char* dyn = (char*)p;
    const size_t used = (size_t)(dyn - (char*)d_ws);

    const size_t slab_gi = (size_t)TCp * 512 * 768;   // shorts
    const size_t slab_ha = (size_t)TCp * 512 * 256;
    const size_t pipe_need = used + (4 * slab_gi + 2 * slab_ha) * sizeof(unsigned short);
    const bool pipe_ok = pipe_need <= ws_size;

    const unsigned short *w0ih = wb + offs[0],  *w0hh = wb + offs[1];
    const unsigned short *b0ih = wb + offs[2],  *b0hh = wb + offs[3];
    const unsigned short *w1ih = wb + offs[4],  *w1hh = wb + offs[5];
    const unsigned short *b1ih = wb + offs[6],  *b1hh = wb + offs[7];
    const unsigned short *lwih0  = wb + offs[8],  *lbih0  = wb + offs[9],  *lbhh0  = wb + offs[10];
    const unsigned short *lwih0r = wb + offs[11], *lbih0r = wb + offs[12], *lbhh0r = wb + offs[13];
    const unsigned short *lwih1  = wb + offs[14], *lbih1  = wb + offs[15], *lbhh1  = wb + offs[16];
    const unsigned short *lwih1r = wb + offs[17], *lbih1r = wb + offs[18], *lbhh1r = wb + offs[19];
    const unsigned short *k1b = wb + offs[20], *k1s = wb + offs[21], *k1c = wb + offs[22];
    const unsigned short *k2b = wb + offs[23], *k2s = wb + offs[24], *k2c = wb + offs[25];

    srt_detect<<<1, 64, 0, stream>>>((const unsigned int*)d_in[0], flag);
    srt_conv<<<1024, 256, 0, stream>>>(ct, wb, flag);
    srt_prep<<<512, 256, 0, stream>>>(h0s, s, bias0, bias1, b0ih, b0hh, b1ih, b1hh, seq);

    if (pipe_ok){
        unsigned short* gi0a = (unsigned short*)dyn;
        unsigned short* gi0b = gi0a + slab_gi;
        unsigned short* haa  = gi0b + slab_gi;
        unsigned short* hab  = haa + slab_ha;
        unsigned short* gi1a = hab + slab_ha;
        unsigned short* gi1b = gi1a + slab_gi;

        PA a;
        a.xv = d_in[0]; a.flag = flag;
        a.w0ih = w0ih; a.w0hh = w0hh; a.b0hh = b0hh;
        a.w1ih = w1ih; a.w1hh = w1hh; a.b1hh = b1hh;
        a.bias0 = bias0; a.bias1 = bias1;
        a.h0s = h0s; a.h1s = s;
        a.gi0a = gi0a; a.gi0b = gi0b; a.haa = haa; a.hab = hab;
        a.gi1a = gi1a; a.gi1b = gi1b;
        for (int ph = 0; ph <= NCp + 2; ++ph){
            a.p = ph;
            srt_phase<<<256, 512, 0, stream>>>(a);
        }
    } else {
        srt_gru<<<128, 256, 0, stream>>>(d_in[0], w0ih, w0hh, b0ih, b0hh,
                                         w1ih, w1hh, b1ih, b1hh, s, flag, seq, hb);
    }

    srt_tail<<<512, 1024, 0, stream>>>(s,
        lwih0, lbih0, lbhh0, lwih0r, lbih0r, lbhh0r,
        lwih1, lbih1, lbhh1, lwih1r, lbih1r, lbhh1r,
        k1b, k1s, k1c, k2b, k2s, k2c, d_out, flag);
}

// Round 8
// 1776.848 us; speedup vs baseline: 1.0418x; 1.0418x over previous
//
#include <hip/hip_runtime.h>
#include <stdint.h>

// SRTKAN v9: v8's counted-vmcnt pipeline with the ring-slot RACE FIXED.
// v8 staged buffer t+2 BEFORE the iteration barrier -> slot (t+2)%3 == (t-1)%3
// was overwritten while slower waves still read it (absmax 2.5e-2). Now all
// staging is issued AFTER wait+s_barrier+sched_barrier, into a provably-free
// slot. Wait ledgers re-derived for the new placement (same latency tolerance:
// loads issued at iter t are needed at iter t+2).

constexpr int B_  = 512;
constexpr int T_  = 512;
constexpr int IN_ = 128;
constexpr int H_  = 256;
constexpr int GR_ = 32;                   // batch groups (fallback path)
constexpr int PL_ = GR_ * 2 * 4096;       // elements per parity plane (fallback path)
constexpr int TCp = 64;                   // pipeline chunk (T steps)
constexpr int NCp = 8;                    // chunks

typedef __attribute__((ext_vector_type(8))) short bf16x8;
typedef __attribute__((ext_vector_type(4))) float f32x4;

#define MFMA16(a, b, c) __builtin_amdgcn_mfma_f32_16x16x32_bf16((a), (b), (c), 0, 0, 0)

__device__ __forceinline__ float bf2f(unsigned short u){
    union { unsigned int i; float f; } v; v.i = ((unsigned int)u) << 16; return v.f;
}
__device__ __forceinline__ unsigned short f2bf(float f){
    union { float f; unsigned int i; } v; v.f = f;
    return (unsigned short)((v.i + 0x7FFFu + ((v.i >> 16) & 1u)) >> 16); // RNE
}
__device__ __forceinline__ unsigned int cvtpk(float a, float b){
    unsigned int r;
    asm("v_cvt_pk_bf16_f32 %0, %1, %2" : "=v"(r) : "v"(a), "v"(b));
    return r;
}
__device__ __forceinline__ unsigned long long pk4(float a, float b, float c, float d){
    const unsigned int lo = cvtpk(a, b), hi = cvtpk(c, d);
    return (unsigned long long)lo | ((unsigned long long)hi << 32);
}
__device__ __forceinline__ float sig_(float x){
    return __builtin_amdgcn_rcpf(1.0f + __expf(-x));
}
__device__ __forceinline__ float tanh_(float x){
    return 1.0f - 2.0f * __builtin_amdgcn_rcpf(1.0f + __expf(2.0f * x));
}
__device__ __forceinline__ bf16x8 ldb8g(const unsigned short* p){ return *(const bf16x8*)p; }

union U64x2 { unsigned long long q[2]; bf16x8 v; };

__device__ __forceinline__ void gl2lds16(const void* g, void* l){
    __builtin_amdgcn_global_load_lds(
        (const __attribute__((address_space(1))) unsigned int*)g,
        (__attribute__((address_space(3))) unsigned int*)l, 16, 0, 0);
}

// ---------------------------------------------------------------------------
// dtype detect
// ---------------------------------------------------------------------------
__global__ void srt_detect(const unsigned int* __restrict__ xw, unsigned int* __restrict__ flag){
    int cnt = 0;
    for (int i = threadIdx.x; i < 1024; i += 64){
        const unsigned int lo = xw[i] & 0xFFFFu;
        const int e = (int)((lo >> 7) & 0xFFu);
        if (e >= 100 && e <= 140) cnt++;
    }
    #pragma unroll
    for (int o = 32; o > 0; o >>= 1) cnt += __shfl_down(cnt, o);
    if (threadIdx.x == 0) *flag = (cnt > 614) ? 1u : 0u;   // 1 = bf16 inputs
}

// ---------------------------------------------------------------------------
// stage weights as bf16
// ---------------------------------------------------------------------------
struct ConvTab { const void* src[26]; int n[26]; int off[26]; };

__global__ __launch_bounds__(256) void srt_conv(ConvTab ct, unsigned short* __restrict__ wb,
                                                const unsigned int* __restrict__ flag){
    const bool isb = (*flag != 0);
    const int gsz = gridDim.x * blockDim.x;
    const int gid = blockIdx.x * blockDim.x + threadIdx.x;
    for (int j = 0; j < 26; ++j){
        const int n = ct.n[j];
        unsigned short* o = wb + ct.off[j];
        if (isb){
            const unsigned short* s = (const unsigned short*)ct.src[j];
            for (int i = gid; i < n; i += gsz) o[i] = s[i];
        } else {
            const float* s = (const float*)ct.src[j];
            for (int i = gid; i < n; i += gsz) o[i] = f2bf(s[i]);
        }
    }
}

// ---------------------------------------------------------------------------
// prep: zero states/counters; fold biases
// ---------------------------------------------------------------------------
__global__ __launch_bounds__(256) void srt_prep(
    float* __restrict__ h0s, float* __restrict__ h1s,
    float* __restrict__ bias0, float* __restrict__ bias1,
    const unsigned short* __restrict__ b0ih, const unsigned short* __restrict__ b0hh,
    const unsigned short* __restrict__ b1ih, const unsigned short* __restrict__ b1hh,
    unsigned int* __restrict__ seq)
{
    const int gid = blockIdx.x * blockDim.x + threadIdx.x;  // grid 512*256
    h0s[gid] = 0.f;
    h1s[gid] = 0.f;
    if (gid < 768){
        bias0[gid] = bf2f(b0ih[gid]) + (gid < 512 ? bf2f(b0hh[gid]) : 0.f);
        bias1[gid] = bf2f(b1ih[gid]) + (gid < 512 ? bf2f(b1hh[gid]) : 0.f);
    }
    if (gid < 1024) seq[gid] = 0u;
}

// ---------------------------------------------------------------------------
// x -> bf16, TIME-MAJOR full-T: xb[(t*512 + b)*128 + c]
// ---------------------------------------------------------------------------
__global__ __launch_bounds__(256) void srt_xconv(
    const void* __restrict__ xv, unsigned short* __restrict__ xb,
    const unsigned int* __restrict__ flagp)
{
    const bool isb = (*flagp != 0);
    const int total = 512 * 512 * 16;      // 16B granules
    const int gsz = gridDim.x * blockDim.x;
    for (int g_ = blockIdx.x * blockDim.x + threadIdx.x; g_ < total; g_ += gsz){
        const int tt  = g_ >> 13;          // / (512*16)
        const int rem = g_ & 8191;
        const int b = rem >> 4, cg = rem & 15;
        const long long s8 = ((long long)b * 512 + tt) * 16 + cg;
        bf16x8 v;
        if (isb){
            v = ((const bf16x8*)xv)[s8];
        } else {
            const float* p = (const float*)xv + s8 * 8;
            const float4 f0 = *(const float4*)p;
            const float4 f1 = *(const float4*)(p + 4);
            unsigned int u0 = cvtpk(f0.x, f0.y), u1 = cvtpk(f0.z, f0.w);
            unsigned int u2 = cvtpk(f1.x, f1.y), u3 = cvtpk(f1.z, f1.w);
            U64x2 w;
            w.q[0] = (unsigned long long)u0 | ((unsigned long long)u1 << 32);
            w.q[1] = (unsigned long long)u2 | ((unsigned long long)u3 << 32);
            v = w.v;
        }
        ((bf16x8*)xb)[g_] = v;
    }
}

// ---------------------------------------------------------------------------
// seq role: one GRU layer, TC steps, 16 batch rows (group bg), 512 threads.
// Ring-3 gi slabs; ONE raw s_barrier/step; counted vmcnt (never 0 in loop).
// STAGING AFTER THE BARRIER (race fix): slot (t+2)%3 freed by iter t-1 and
// certified free by this barrier.
// Wait ledger (own-wave, in-order): slab t staged at iter t-2 (or prologue).
//   h_all:   t=0 -> after slab0: slab1(6)                  -> vmcnt(6)
//            t=1 -> after slab1: slab2(6)+stores0(2)       -> vmcnt(8)
//            t>=2-> after slab t: st(t-2)(2)+slab t+1(6)+st(t-1)(2) -> vmcnt(10)
//   no h_all: always 6 loads after -> vmcnt(6)
// shm carve: wnL[32768] | hbuf[2*4096] @32768 | gib[3*12288] @40960  (152 KB)
// ---------------------------------------------------------------------------
__device__ void seq_dev(unsigned short* shm,
    const unsigned short* __restrict__ gi,
    const unsigned short* __restrict__ whh,
    const unsigned short* __restrict__ bhh,
    float* __restrict__ hstate,
    unsigned short* __restrict__ h_all,
    const int TC, const int bg)
{
    unsigned short* wnL   = shm;
    unsigned short* hbufB = shm + 32768;
    unsigned short* gibB  = shm + 40960;

    const int tid  = threadIdx.x;
    const int lane = tid & 63;
    const int wv   = tid >> 6;
    const int l15  = lane & 15;
    const int quad = lane >> 4;
    const int m0   = bg * 16;
    const int swz  = (l15 & 7) << 4;

    bf16x8 wr[5][8];
    #pragma unroll
    for (int fi = 0; fi < 6; ++fi){
        const int u = fi >> 1, ii = fi & 1;
        const unsigned short* wp =
            whh + (size_t)(u * 256 + wv * 32 + ii * 16 + l15) * 256 + quad * 8;
        if (fi < 5){
            #pragma unroll
            for (int kc = 0; kc < 8; ++kc) wr[fi][kc] = ldb8g(wp + kc * 32);
        } else {
            #pragma unroll
            for (int kc = 0; kc < 8; ++kc)
                *(bf16x8*)&wnL[((wv * 8 + kc) << 9) + lane * 8] = ldb8g(wp + kc * 32);
        }
    }

    f32x4 bn0[2];
    #pragma unroll
    for (int ii = 0; ii < 2; ++ii)
        #pragma unroll
        for (int j = 0; j < 4; ++j)
            bn0[ii][j] = bf2f(bhh[512 + wv * 32 + ii * 16 + quad * 4 + j]);

    f32x4 hr[2];
    #pragma unroll
    for (int ii = 0; ii < 2; ++ii)
        hr[ii] = *(const f32x4*)&hstate[(size_t)(m0 + l15) * 256 + wv * 32 + ii * 16 + quad * 4];

    const unsigned short* gpp[3]; int gdl[3];
    #pragma unroll
    for (int i = 0; i < 3; ++i){
        const int g_  = i * 512 + tid;
        const int row = g_ / 96;
        const int cg  = g_ - row * 96;
        gpp[i] = gi + ((size_t)m0 + row) * 768 + ((cg ^ (row & 7)) << 3);
        gdl[i] = g_ * 8;
    }

    // prologue: publish h(init) -> hbuf[0]; stage slab 0 -> slot0, slab 1 -> slot1
    #pragma unroll
    for (int ii = 0; ii < 2; ++ii){
        const unsigned long long pk = pk4(hr[ii][0], hr[ii][1], hr[ii][2], hr[ii][3]);
        *(unsigned long long*)((char*)hbufB + l15 * 512 +
            ((wv * 64 + ii * 32 + quad * 8) ^ swz)) = pk;
    }
    #pragma unroll
    for (int i = 0; i < 3; ++i) gl2lds16(gpp[i], &gibB[gdl[i]]);
    #pragma unroll
    for (int i = 0; i < 3; ++i) gl2lds16(gpp[i] + (size_t)(512 * 768), &gibB[12288 + gdl[i]]);

    #pragma unroll 1
    for (int t = 0; t < TC; ++t){
        const int par = t & 1;
        unsigned short* hb_cur = hbufB + par * 4096;
        unsigned short* hb_nxt = hbufB + (par ^ 1) * 4096;
        unsigned short* gb_cur = gibB + (t % 3) * 12288;

        // certify slab t + own ds_writes; then barrier; THEN stage (race-free)
        if (h_all){
            if (t >= 2)      asm volatile("s_waitcnt vmcnt(10) lgkmcnt(0)" ::: "memory");
            else if (t == 1) asm volatile("s_waitcnt vmcnt(8) lgkmcnt(0)" ::: "memory");
            else             asm volatile("s_waitcnt vmcnt(6) lgkmcnt(0)" ::: "memory");
        } else {
            asm volatile("s_waitcnt vmcnt(6) lgkmcnt(0)" ::: "memory");
        }
        __builtin_amdgcn_s_barrier();
        __builtin_amdgcn_sched_barrier(0);

        // stage slab t+2 into slot (t+2)%3 (freed by iter t-1, certified by barrier).
        // Clamped at tail: dead stage into a permanently-free slot keeps counts uniform.
        {
            const int ts = (t + 2 < TC) ? (t + 2) : (TC - 1);
            unsigned short* gb_pre = gibB + ((t + 2) % 3) * 12288;
            const size_t toff = (size_t)ts * (512 * 768);
            #pragma unroll
            for (int i = 0; i < 3; ++i) gl2lds16(gpp[i] + toff, &gb_pre[gdl[i]]);
        }

        f32x4 aR0 = {0,0,0,0}, aR1 = {0,0,0,0}, aZ0 = {0,0,0,0}, aZ1 = {0,0,0,0};
        f32x4 aN0 = bn0[0], aN1 = bn0[1];
        __builtin_amdgcn_s_setprio(1);
        #pragma unroll
        for (int kc = 0; kc < 8; ++kc){
            const bf16x8 hb = *(const bf16x8*)((const char*)hb_cur +
                l15 * 512 + ((kc * 64 + quad * 16) ^ swz));
            const bf16x8 w5 = *(const bf16x8*)&wnL[((wv * 8 + kc) << 9) + lane * 8];
            aR0 = MFMA16(wr[0][kc], hb, aR0);
            aR1 = MFMA16(wr[1][kc], hb, aR1);
            aZ0 = MFMA16(wr[2][kc], hb, aZ0);
            aZ1 = MFMA16(wr[3][kc], hb, aZ1);
            aN0 = MFMA16(wr[4][kc], hb, aN0);
            aN1 = MFMA16(w5,        hb, aN1);
        }
        __builtin_amdgcn_s_setprio(0);

        const char* gbase = (const char*)gb_cur + l15 * 1536;
        #pragma unroll
        for (int ii = 0; ii < 2; ++ii){
            const int cb = wv * 64 + ii * 32 + quad * 8;
            const unsigned long long qr = *(const unsigned long long*)(gbase + ((       cb) ^ swz));
            const unsigned long long qz = *(const unsigned long long*)(gbase + ((512  + cb) ^ swz));
            const unsigned long long qn = *(const unsigned long long*)(gbase + ((1024 + cb) ^ swz));
            const f32x4 aR = ii ? aR1 : aR0;
            const f32x4 aZ = ii ? aZ1 : aZ0;
            const f32x4 aN = ii ? aN1 : aN0;
            #pragma unroll
            for (int j = 0; j < 4; ++j){
                const float rr = sig_(aR[j] + bf2f((unsigned short)(qr >> (16 * j))));
                const float zz = sig_(aZ[j] + bf2f((unsigned short)(qz >> (16 * j))));
                const float nn = tanh_(bf2f((unsigned short)(qn >> (16 * j))) + rr * aN[j]);
                hr[ii][j] = (1.0f - zz) * nn + zz * hr[ii][j];
            }
        }

        #pragma unroll
        for (int ii = 0; ii < 2; ++ii){
            const unsigned long long pk = pk4(hr[ii][0], hr[ii][1], hr[ii][2], hr[ii][3]);
            *(unsigned long long*)((char*)hb_nxt + l15 * 512 +
                ((wv * 64 + ii * 32 + quad * 8) ^ swz)) = pk;
            if (h_all)
                *(unsigned long long*)(h_all + ((size_t)t * 512 + m0 + l15) * 256 +
                    wv * 32 + ii * 16 + quad * 4) = pk;
        }
        // no end-of-step barrier: next step's top wait+barrier covers hbuf & gi
    }
    asm volatile("s_waitcnt vmcnt(0)" ::: "memory");

    #pragma unroll
    for (int ii = 0; ii < 2; ++ii)
        *(f32x4*)&hstate[(size_t)(m0 + l15) * 256 + wv * 32 + ii * 16 + quad * 4] = hr[ii];
}

// ---------------------------------------------------------------------------
// gemm role: deep loop + counted vmcnt, STAGING AFTER BARRIER (race fix).
// Block owns feat half-tile nb (64 of 768) and M-group mg (4096 rows).
// W[64xK] resident (frags in regs); A chunks [128x64] ring-3 staged 2 ahead.
// Wait ledger: chunk it staged at iter it-2 (after that barrier).
//   it<2 or kk>=2: after chunk it = chunk it+1 (2)            -> vmcnt(2)
//   it>=2 and kk<2: + 8 C-stores of the prev M-tile interleave -> vmcnt(10)
// shm carve: Wt[64*K] @0 | Ab[3*8192] @16384.
// ---------------------------------------------------------------------------
template<int K>
__device__ void gemm_dev(unsigned short* shm, const unsigned short* __restrict__ A,
                         const unsigned short* __restrict__ W,
                         const float* __restrict__ bias,
                         unsigned short* __restrict__ C,
                         const int nb, const int mg)
{
    unsigned short* Wt = shm;                   // 64*K shorts (16/32 KB)
    unsigned short* Ab = shm + 16384;           // 3 * 8192 shorts (48 KB)

    const int tid = threadIdx.x;                // 0..511
    const int lane = tid & 63, wv = tid >> 6;
    const int l15 = lane & 15, quad = lane >> 4;
    const int fh = wv & 1, mq = wv >> 1;        // feat-half(32), M-quarter(32 rows)
    constexpr int NK  = K / 64;                 // A chunks per M-tile
    constexpr int GW  = K / 8;                  // W granules per row
    constexpr int WG  = 64 * GW / 512;          // W granules per thread
    constexpr int NIT = 32 * NK;

    // ---- stage resident W tile
    #pragma unroll
    for (int i = 0; i < WG; ++i){
        const int g_ = i * 512 + tid;
        const int row = g_ / GW, cg = g_ % GW;
        gl2lds16(W + (size_t)(nb * 64 + row) * K + ((cg ^ (row & 7)) << 3), &Wt[g_ * 8]);
    }

    float bs[2][4];
    #pragma unroll
    for (int ni = 0; ni < 2; ++ni)
        #pragma unroll
        for (int j = 0; j < 4; ++j)
            bs[ni][j] = bias[nb * 64 + fh * 32 + ni * 16 + quad * 4 + j];

    // A chunk stager: chunk index ic -> M-tile ic/NK, k-chunk ic%NK, slot
    auto stageA = [&](int ic, int slot){
        const int mt = ic / NK, kk = ic % NK;
        unsigned short* dst = Ab + slot * 8192;
        #pragma unroll
        for (int i = 0; i < 2; ++i){
            const int g_ = i * 512 + tid;
            const int row = g_ >> 3, cg = g_ & 7;
            gl2lds16(A + (size_t)(mg * 4096 + mt * 128 + row) * K + kk * 64 +
                     ((cg ^ (row & 7)) << 3), &dst[g_ * 8]);
        }
    };

    stageA(0, 0);
    stageA(1, 1);
    // W certified when outstanding <= 4 (= c0,c1); barrier; hoist W frags
    asm volatile("s_waitcnt vmcnt(4)" ::: "memory");
    __builtin_amdgcn_s_barrier();
    __builtin_amdgcn_sched_barrier(0);

    bf16x8 wf[2][2 * NK];
    #pragma unroll
    for (int ni = 0; ni < 2; ++ni)
        #pragma unroll
        for (int k2 = 0; k2 < 2 * NK; ++k2){
            const int rf = fh * 32 + ni * 16 + l15;
            wf[ni][k2] = *(const bf16x8*)((const char*)Wt +
                rf * (2 * K) + (((k2 * 4 + quad) ^ (rf & 7)) << 4));
        }

    #pragma unroll 1
    for (int mt = 0; mt < 32; ++mt){
        f32x4 acc[2][2];
        #pragma unroll
        for (int ni = 0; ni < 2; ++ni){
            acc[ni][0] = (f32x4){0,0,0,0};
            acc[ni][1] = (f32x4){0,0,0,0};
        }

        #pragma unroll
        for (int kk = 0; kk < NK; ++kk){
            const int it = mt * NK + kk;
            // certify chunk it, then barrier, THEN stage into the freed slot
            if (it >= 2 && kk < 2) asm volatile("s_waitcnt vmcnt(10)" ::: "memory");
            else                   asm volatile("s_waitcnt vmcnt(2)"  ::: "memory");
            __builtin_amdgcn_s_barrier();
            __builtin_amdgcn_sched_barrier(0);
            // clamped tail staging keeps per-iter load counts uniform; dead
            // stages land in slots never read again
            stageA((it + 2 < NIT) ? (it + 2) : (NIT - 1), (it + 2) % 3);

            const char* ab = (const char*)(Ab + (it % 3) * 8192);
            #pragma unroll
            for (int kc = 0; kc < 2; ++kc){
                bf16x8 af[2];
                #pragma unroll
                for (int mi = 0; mi < 2; ++mi){
                    const int ra = mq * 32 + mi * 16 + l15;
                    af[mi] = *(const bf16x8*)(ab + ra * 128 +
                              (((kc * 4 + quad) ^ (ra & 7)) << 4));
                }
                #pragma unroll
                for (int ni = 0; ni < 2; ++ni)
                    #pragma unroll
                    for (int mi = 0; mi < 2; ++mi)
                        acc[ni][mi] = MFMA16(wf[ni][kk * 2 + kc], af[mi], acc[ni][mi]);
            }
        }

        // store M-tile: D[m=feat quad*4+j][n=row l15] -> b64 of 4 feats
        #pragma unroll
        for (int ni = 0; ni < 2; ++ni)
            #pragma unroll
            for (int mi = 0; mi < 2; ++mi){
                const unsigned int lo = cvtpk(acc[ni][mi][0] + bs[ni][0],
                                              acc[ni][mi][1] + bs[ni][1]);
                const unsigned int hi = cvtpk(acc[ni][mi][2] + bs[ni][2],
                                              acc[ni][mi][3] + bs[ni][3]);
                const int row = mg * 4096 + mt * 128 + mq * 32 + mi * 16 + l15;
                const int col = nb * 64 + fh * 32 + ni * 16 + quad * 4;
                uint2 st; st.x = lo; st.y = hi;
                *(uint2*)(C + (size_t)row * 768 + col) = st;
            }
    }
    asm volatile("s_waitcnt vmcnt(0)" ::: "memory");
}

// ---------------------------------------------------------------------------
// phase kernel: grid = 256 (1 block/CU). block = 512, 152 KB LDS.
//  [0,32) seq0(p-1) | [32,64) seq1(p-3) | [64,160) gemmx(p) | [160,256) gemm1(p-2)
// ---------------------------------------------------------------------------
struct PA {
    const unsigned short* xb;
    const unsigned short *w0ih, *w0hh, *b0hh, *w1ih, *w1hh, *b1hh;
    const float *bias0, *bias1;
    float *h0s, *h1s;
    unsigned short *gi0a, *gi0b, *haa, *hab, *gi1a, *gi1b;
    int p;
};

__global__ __launch_bounds__(512, 1) void srt_phase(PA a){
    __shared__ __align__(16) unsigned short shm[77824];   // 152 KB
    const int bid = blockIdx.x;
    const int p = a.p;

    if (bid < 32){
        const int c = p - 1; if (c < 0 || c >= NCp) return;
        seq_dev(shm, (c & 1) ? a.gi0b : a.gi0a, a.w0hh, a.b0hh, a.h0s,
                (c & 1) ? a.hab : a.haa, TCp, bid);
    } else if (bid < 64){
        const int c = p - 3; if (c < 0 || c >= NCp) return;
        seq_dev(shm, (c & 1) ? a.gi1b : a.gi1a, a.w1hh, a.b1hh, a.h1s,
                nullptr, TCp, bid - 32);
    } else if (bid < 160){
        const int c = p; if (c >= NCp) return;
        const int idx = bid - 64;
        gemm_dev<128>(shm, a.xb + (size_t)c * (TCp * 512 * 128), a.w0ih, a.bias0,
                      (c & 1) ? a.gi0b : a.gi0a, idx % 12, idx / 12);
    } else {
        const int c = p - 2; if (c < 0 || c >= NCp) return;
        const int idx = bid - 160;
        gemm_dev<256>(shm, (c & 1) ? a.hab : a.haa, a.w1ih, a.bias1,
                      (c & 1) ? a.gi1b : a.gi1a, idx % 12, idx / 12);
    }
}

// ---------------------------------------------------------------------------
// OLD PATH (fallback when ws_size too small): persistent GRU with LLC exchange.
// ---------------------------------------------------------------------------
__global__ __launch_bounds__(256, 1) void srt_gru(
    const void* __restrict__ xv,
    const unsigned short* __restrict__ w0ih,
    const unsigned short* __restrict__ w0hh,
    const unsigned short* __restrict__ b0ih,
    const unsigned short* __restrict__ b0hh,
    const unsigned short* __restrict__ w1ih,
    const unsigned short* __restrict__ w1hh,
    const unsigned short* __restrict__ b1ih,
    const unsigned short* __restrict__ b1hh,
    float* __restrict__ s_out,
    const unsigned int* __restrict__ flagp,
    unsigned int* __restrict__ seq,
    unsigned short* __restrict__ hb)
{
    __shared__ __align__(16) unsigned short w0hhL[4 * 24 * 512];

    const bool isb = (*flagp != 0);
    const int tid  = threadIdx.x;
    const int lane = tid & 63;
    const int wv   = tid >> 6;
    const int l15  = lane & 15;
    const int quad = lane >> 4;
    const int q    = blockIdx.x >> 5;
    const int g    = blockIdx.x & 31;
    const int m0   = g * 16;
    const int c    = q * 64 + wv * 16 + l15;

    bf16x8 w0ihr[3][4];
    #pragma unroll
    for (int u = 0; u < 3; ++u)
        #pragma unroll
        for (int kc = 0; kc < 4; ++kc)
            w0ihr[u][kc] = ldb8g(w0ih + (u * 256 + c) * IN_ + kc * 32 + quad * 8);

    bf16x8 w1ihr[3][8], w1hhr[3][8];
    #pragma unroll
    for (int u = 0; u < 3; ++u)
        #pragma unroll
        for (int kc = 0; kc < 8; ++kc){
            w1ihr[u][kc] = ldb8g(w1ih + (u * 256 + c) * H_ + kc * 32 + quad * 8);
            w1hhr[u][kc] = ldb8g(w1hh + (u * 256 + c) * H_ + kc * 32 + quad * 8);
        }

    const int wl = wv * 12288 + lane * 8;
    #pragma unroll
    for (int u = 0; u < 3; ++u)
        #pragma unroll
        for (int kc = 0; kc < 8; ++kc){
            const bf16x8 f = ldb8g(w0hh + (u * 256 + c) * H_ + kc * 32 + quad * 8);
            *(bf16x8*)&w0hhL[wl + (u * 8 + kc) * 512] = f;
        }

    const float brz0a = bf2f(b0ih[c])       + bf2f(b0hh[c]);
    const float brz0b = bf2f(b0ih[256 + c]) + bf2f(b0hh[256 + c]);
    const float bni0v = bf2f(b0ih[512 + c]);
    const float bnh0v = bf2f(b0hh[512 + c]);
    const float brz1a = bf2f(b1ih[c])       + bf2f(b1hh[c]);
    const float brz1b = bf2f(b1ih[256 + c]) + bf2f(b1hh[256 + c]);
    const float bni1v = bf2f(b1ih[512 + c]);
    const float bnh1v = bf2f(b1hh[512 + c]);
    __syncthreads();

    float h0r[4] = {0.f, 0.f, 0.f, 0.f};
    float h1r[4] = {0.f, 0.f, 0.f, 0.f};

    const size_t xrow = (size_t)(m0 + l15) * (T_ * IN_) + quad * 8;
    const unsigned short* pxb = (const unsigned short*)xv + xrow;
    const float*          pxf = (const float*)xv + xrow;

    unsigned int* sq = seq + g * 32;
    const int wr_row[4] = {(quad * 4 + 0) * 256 + c, (quad * 4 + 1) * 256 + c,
                           (quad * 4 + 2) * 256 + c, (quad * 4 + 3) * 256 + c};

    const f32x4 z4 = {0.f, 0.f, 0.f, 0.f};
    bf16x8 h0A[8], h1A[8];
    #pragma unroll
    for (int kc = 0; kc < 8; ++kc){
        h0A[kc] = (bf16x8)(short)0;
        h1A[kc] = (bf16x8)(short)0;
    }

    #pragma unroll 1
    for (int t = 0; t < T_; ++t){
        const int par = t & 1;
        const unsigned int tgt = 4u * (unsigned)(t + 1);
        unsigned short* plane = hb + par * PL_ + g * (2 * 4096);

        #pragma unroll
        for (int j = 0; j < 4; ++j)
            __hip_atomic_store(&plane[4096 + wr_row[j]], f2bf(h1r[j]),
                               __ATOMIC_RELAXED, __HIP_MEMORY_SCOPE_AGENT);

        bf16x8 ax[4];
        if (isb){
            #pragma unroll
            for (int kc = 0; kc < 4; ++kc) ax[kc] = ldb8g(pxb + t * IN_ + kc * 32);
        } else {
            #pragma unroll
            for (int kc = 0; kc < 4; ++kc){
                const float* p = pxf + t * IN_ + kc * 32;
                const float4 f0 = *(const float4*)p;
                const float4 f1 = *(const float4*)(p + 4);
                bf16x8 a;
                a[0] = (short)f2bf(f0.x); a[1] = (short)f2bf(f0.y);
                a[2] = (short)f2bf(f0.z); a[3] = (short)f2bf(f0.w);
                a[4] = (short)f2bf(f1.x); a[5] = (short)f2bf(f1.y);
                a[6] = (short)f2bf(f1.z); a[7] = (short)f2bf(f1.w);
                ax[kc] = a;
            }
        }

        f32x4 Tr = z4, Tz = z4, Tni = z4, Tnh = z4;
        #pragma unroll
        for (int kc = 0; kc < 4; ++kc){
            Tr  = MFMA16(ax[kc], w0ihr[0][kc], Tr);
            Tz  = MFMA16(ax[kc], w0ihr[1][kc], Tz);
            Tni = MFMA16(ax[kc], w0ihr[2][kc], Tni);
        }
        #pragma unroll
        for (int kc = 0; kc < 8; ++kc){
            const bf16x8 a = h0A[kc];
            Tr  = MFMA16(a, *(const bf16x8*)&w0hhL[wl + (0 * 8 + kc) * 512], Tr);
            Tz  = MFMA16(a, *(const bf16x8*)&w0hhL[wl + (1 * 8 + kc) * 512], Tz);
            Tnh = MFMA16(a, *(const bf16x8*)&w0hhL[wl + (2 * 8 + kc) * 512], Tnh);
        }
        #pragma unroll
        for (int j = 0; j < 4; ++j){
            const float rr = sig_(Tr[j] + brz0a);
            const float zz = sig_(Tz[j] + brz0b);
            const float nn = tanh_(Tni[j] + bni0v + rr * (Tnh[j] + bnh0v));
            h0r[j] = (1.0f - zz) * nn + zz * h0r[j];
        }

        #pragma unroll
        for (int j = 0; j < 4; ++j)
            __hip_atomic_store(&plane[wr_row[j]], f2bf(h0r[j]),
                               __ATOMIC_RELAXED, __HIP_MEMORY_SCOPE_AGENT);

        __syncthreads();
        if (tid == 0)
            __hip_atomic_fetch_add(sq, 1u, __ATOMIC_RELAXED, __HIP_MEMORY_SCOPE_AGENT);
        if (lane == 0){
            while (__hip_atomic_load(sq, __ATOMIC_RELAXED, __HIP_MEMORY_SCOPE_AGENT) < tgt)
                __builtin_amdgcn_s_sleep(1);
        }
        __atomic_signal_fence(__ATOMIC_ACQ_REL);

        {
            const unsigned short* r0 = plane + l15 * 256 + quad * 8;
            #pragma unroll
            for (int kc = 0; kc < 8; ++kc){
                U64x2 u0, u1;
                u0.q[0] = __hip_atomic_load((const unsigned long long*)(r0 + kc * 32),
                                            __ATOMIC_RELAXED, __HIP_MEMORY_SCOPE_AGENT);
                u0.q[1] = __hip_atomic_load((const unsigned long long*)(r0 + kc * 32 + 4),
                                            __ATOMIC_RELAXED, __HIP_MEMORY_SCOPE_AGENT);
                u1.q[0] = __hip_atomic_load((const unsigned long long*)(r0 + 4096 + kc * 32),
                                            __ATOMIC_RELAXED, __HIP_MEMORY_SCOPE_AGENT);
                u1.q[1] = __hip_atomic_load((const unsigned long long*)(r0 + 4096 + kc * 32 + 4),
                                            __ATOMIC_RELAXED, __HIP_MEMORY_SCOPE_AGENT);
                h0A[kc] = u0.v;
                h1A[kc] = u1.v;
            }
        }

        Tr = z4; Tz = z4; Tni = z4; Tnh = z4;
        #pragma unroll
        for (int kc = 0; kc < 8; ++kc){
            const bf16x8 a0 = h0A[kc];
            const bf16x8 a1 = h1A[kc];
            Tr  = MFMA16(a0, w1ihr[0][kc], Tr);
            Tr  = MFMA16(a1, w1hhr[0][kc], Tr);
            Tz  = MFMA16(a0, w1ihr[1][kc], Tz);
            Tz  = MFMA16(a1, w1hhr[1][kc], Tz);
            Tni = MFMA16(a0, w1ihr[2][kc], Tni);
            Tnh = MFMA16(a1, w1hhr[2][kc], Tnh);
        }
        #pragma unroll
        for (int j = 0; j < 4; ++j){
            const float rr = sig_(Tr[j] + brz1a);
            const float zz = sig_(Tz[j] + brz1b);
            const float nn = tanh_(Tni[j] + bni1v + rr * (Tnh[j] + bnh1v));
            h1r[j] = (1.0f - zz) * nn + zz * h1r[j];
        }
    }

    #pragma unroll
    for (int j = 0; j < 4; ++j)
        s_out[(size_t)(m0 + quad * 4 + j) * H_ + c] = h1r[j];
}

// ---------------------------------------------------------------------------
// B-spline basis (uniform grid, GRID_SIZE=5, ORDER=3)
// ---------------------------------------------------------------------------
__device__ __forceinline__ float knot_(int p){ return (float)(p - 3) * 0.4f - 1.0f; }

__device__ __forceinline__ void bspline8(float xv, float* bb8){
    float bb[11];
    #pragma unroll
    for (int p = 0; p < 11; ++p)
        bb[p] = (xv >= knot_(p) && xv < knot_(p + 1)) ? 1.f : 0.f;
    #pragma unroll
    for (int k = 1; k <= 3; ++k){
        #pragma unroll
        for (int p = 0; p <= 10 - k; ++p){
            const float tp = knot_(p), tpk = knot_(p + k);
            const float tp1 = knot_(p + 1), tpk1 = knot_(p + k + 1);
            bb[p] = (xv - tp) / (tpk - tp) * bb[p] + (tpk1 - xv) / (tpk1 - tp1) * bb[p + 1];
        }
    }
    #pragma unroll
    for (int j = 0; j < 8; ++j) bb8[j] = bb[j];
}

// partial LSTM dots over k in [k0, k0+64) for 3 gates (i,g,o) of unit uu
__device__ __forceinline__ void lstm_part(const float* sxv, const unsigned short* w,
                                          int uu, int k0, float* out3){
    const unsigned short* wi = w + (size_t)uu * 256 + k0;
    const unsigned short* wg = w + (size_t)(256 + uu) * 256 + k0;
    const unsigned short* wo = w + (size_t)(384 + uu) * 256 + k0;
    float ai = 0.f, ag = 0.f, ao = 0.f;
    for (int k = 0; k < 64; k += 8){
        const bf16x8 vi = ldb8g(wi + k);
        const bf16x8 vg = ldb8g(wg + k);
        const bf16x8 vo = ldb8g(wo + k);
        #pragma unroll
        for (int j = 0; j < 8; ++j){
            const float s = sxv[k0 + k + j];
            ai += bf2f((unsigned short)vi[j]) * s;
            ag += bf2f((unsigned short)vg[j]) * s;
            ao += bf2f((unsigned short)vo[j]) * s;
        }
    }
    out3[0] = ai; out3[1] = ag; out3[2] = ao;
}

// ---------------------------------------------------------------------------
// Fused tail: 1024 threads, 4-way k-split LSTMs + 16-way KAN splits.
// ---------------------------------------------------------------------------
__global__ __launch_bounds__(1024) void srt_tail(
    const float* __restrict__ in,
    const unsigned short* __restrict__ w0f, const unsigned short* __restrict__ bi0f,
    const unsigned short* __restrict__ bh0f,
    const unsigned short* __restrict__ w0r, const unsigned short* __restrict__ bi0r,
    const unsigned short* __restrict__ bh0r,
    const unsigned short* __restrict__ w1f, const unsigned short* __restrict__ bi1f,
    const unsigned short* __restrict__ bh1f,
    const unsigned short* __restrict__ w1r, const unsigned short* __restrict__ bi1r,
    const unsigned short* __restrict__ bh1r,
    const unsigned short* __restrict__ k1b, const unsigned short* __restrict__ k1s,
    const unsigned short* __restrict__ k1c,
    const unsigned short* __restrict__ k2b, const unsigned short* __restrict__ k2s,
    const unsigned short* __restrict__ k2c,
    void* __restrict__ outp,
    const unsigned int* __restrict__ flagp)
{
    __shared__ float sx[256];
    __shared__ float sy[256];
    __shared__ float part[4][256][3];
    __shared__ float sil[256];
    __shared__ float spl[256][8];
    __shared__ float red16[64][16];
    __shared__ float sil2[64];
    __shared__ float spl2[64][8];
    __shared__ float red2[10][16];

    const int b = blockIdx.x, tid = threadIdx.x;
    const int qr = tid >> 8, sub = tid & 255;
    const int dir = sub >> 7, uu = sub & 127;

    if (tid < 256) sx[tid] = in[b * 256 + tid];
    __syncthreads();

    float p3[3];
    lstm_part(sx, dir ? w0r : w0f, uu, qr * 64, p3);
    part[qr][sub][0] = p3[0]; part[qr][sub][1] = p3[1]; part[qr][sub][2] = p3[2];
    __syncthreads();
    if (tid < 256){
        const unsigned short* bi = dir ? bi0r : bi0f;
        const unsigned short* bh = dir ? bh0r : bh0f;
        const float ai = part[0][sub][0] + part[1][sub][0] + part[2][sub][0] + part[3][sub][0];
        const float ag = part[0][sub][1] + part[1][sub][1] + part[2][sub][1] + part[3][sub][1];
        const float ao = part[0][sub][2] + part[1][sub][2] + part[2][sub][2] + part[3][sub][2];
        const float gi = ai + bf2f(bi[uu])       + bf2f(bh[uu]);
        const float gg = ag + bf2f(bi[256 + uu]) + bf2f(bh[256 + uu]);
        const float go = ao + bf2f(bi[384 + uu]) + bf2f(bh[384 + uu]);
        sy[sub] = sig_(go) * tanh_(sig_(gi) * tanh_(gg));
    }
    __syncthreads();

    lstm_part(sy, dir ? w1r : w1f, uu, qr * 64, p3);
    part[qr][sub][0] = p3[0]; part[qr][sub][1] = p3[1]; part[qr][sub][2] = p3[2];
    __syncthreads();
    if (tid < 256){
        const unsigned short* bi = dir ? bi1r : bi1f;
        const unsigned short* bh = dir ? bh1r : bh1f;
        const float ai = part[0][sub][0] + part[1][sub][0] + part[2][sub][0] + part[3][sub][0];
        const float ag = part[0][sub][1] + part[1][sub][1] + part[2][sub][1] + part[3][sub][1];
        const float ao = part[0][sub][2] + part[1][sub][2] + part[2][sub][2] + part[3][sub][2];
        const float gi = ai + bf2f(bi[uu])       + bf2f(bh[uu]);
        const float gg = ag + bf2f(bi[256 + uu]) + bf2f(bh[256 + uu]);
        const float go = ao + bf2f(bi[384 + uu]) + bf2f(bh[384 + uu]);
        const float o1v = sig_(go) * tanh_(sig_(gi) * tanh_(gg));
        sil[sub] = o1v * sig_(o1v);
        float bb[8];
        bspline8(o1v, bb);
        #pragma unroll
        for (int j = 0; j < 8; ++j) spl[sub][j] = bb[j];
    }
    __syncthreads();

    {
        const int o = tid >> 4, q16 = tid & 15;
        float acc = 0.f;
        for (int k = q16 * 16; k < q16 * 16 + 16; ++k){
            acc += sil[k] * bf2f(k1b[o * 256 + k]);
            float t = 0.f;
            #pragma unroll
            for (int j = 0; j < 8; ++j) t += spl[k][j] * bf2f(k1s[(o * 256 + k) * 8 + j]);
            acc += t * bf2f(k1c[o * 256 + k]);
        }
        red16[o][q16] = acc;
    }
    __syncthreads();
    if (tid < 64){
        float zv = 0.f;
        #pragma unroll
        for (int i = 0; i < 16; ++i) zv += red16[tid][i];
        sil2[tid] = zv * sig_(zv);
        float b2[8];
        bspline8(zv, b2);
        #pragma unroll
        for (int j = 0; j < 8; ++j) spl2[tid][j] = b2[j];
    }
    __syncthreads();

    if (tid < 160){
        const int o2 = tid >> 4, q = tid & 15;
        float a2 = 0.f;
        for (int k = q * 4; k < q * 4 + 4; ++k){
            a2 += sil2[k] * bf2f(k2b[o2 * 64 + k]);
            float t = 0.f;
            #pragma unroll
            for (int j = 0; j < 8; ++j) t += spl2[k][j] * bf2f(k2s[(o2 * 64 + k) * 8 + j]);
            a2 += t * bf2f(k2c[o2 * 64 + k]);
        }
        red2[o2][q] = a2;
    }
    __syncthreads();
    if (tid < 10){
        float a2 = 0.f;
        #pragma unroll
        for (int i = 0; i < 16; ++i) a2 += red2[tid][i];
        if (*flagp) ((unsigned short*)outp)[b * 10 + tid] = f2bf(a2);
        else        ((float*)outp)[b * 10 + tid] = a2;
    }
}

extern "C" void kernel_launch(void* const* d_in, const int* in_sizes, int n_in,
                              void* d_out, int out_size, void* d_ws, size_t ws_size,
                              hipStream_t stream)
{
    unsigned int* flag = (unsigned int*)d_ws;
    float* s = (float*)((char*)d_ws + 16);            // final h1 (fp32)
    unsigned short* wb = (unsigned short*)(s + 512 * 256);

    const int idxs[26] = {1,2,3,4,5,6,7,8, 9,11,12, 13,15,16, 17,19,20, 21,23,24,
                          25,26,27, 28,29,30};
    ConvTab ct;
    int off = 0;
    int offs[26];
    for (int j = 0; j < 26; ++j){
        ct.src[j] = d_in[idxs[j]];
        ct.n[j]   = in_sizes[idxs[j]];
        ct.off[j] = off;
        offs[j]   = off;
        off += in_sizes[idxs[j]];
    }
    uintptr_t p = (uintptr_t)(wb + off);
    p = (p + 255) & ~(uintptr_t)255;
    unsigned int* seq = (unsigned int*)p;                 // fallback counters
    unsigned short* hb = (unsigned short*)(seq + 1024);   // fallback exchange buf
    p = (uintptr_t)(hb + 2 * 32 * 2 * 4096);
    p = (p + 255) & ~(uintptr_t)255;
    float* h0s   = (float*)p;                             // 512*256 fp32 layer-0 state
    float* bias0 = h0s + 512 * 256;
    float* bias1 = bias0 + 768;
    p = (uintptr_t)(bias1 + 768);
    p = (p + 255) & ~(uintptr_t)255;
    char* dyn = (char*)p;
    const size_t used = (size_t)(dyn - (char*)d_ws);

    const size_t xb_sz    = (size_t)512 * 512 * 128;  // shorts
    const size_t slab_gi  = (size_t)TCp * 512 * 768;
    const size_t slab_ha  = (size_t)TCp * 512 * 256;
    const size_t pipe_need = used + (xb_sz + 4 * slab_gi + 2 * slab_ha) * sizeof(unsigned short);
    const bool pipe_ok = pipe_need <= ws_size;

    const unsigned short *w0ih = wb + offs[0],  *w0hh = wb + offs[1];
    const unsigned short *b0ih = wb + offs[2],  *b0hh = wb + offs[3];
    const unsigned short *w1ih = wb + offs[4],  *w1hh = wb + offs[5];
    const unsigned short *b1ih = wb + offs[6],  *b1hh = wb + offs[7];
    const unsigned short *lwih0  = wb + offs[8],  *lbih0  = wb + offs[9],  *lbhh0  = wb + offs[10];
    const unsigned short *lwih0r = wb + offs[11], *lbih0r = wb + offs[12], *lbhh0r = wb + offs[13];
    const unsigned short *lwih1  = wb + offs[14], *lbih1  = wb + offs[15], *lbhh1  = wb + offs[16];
    const unsigned short *lwih1r = wb + offs[17], *lbih1r = wb + offs[18], *lbhh1r = wb + offs[19];
    const unsigned short *k1b = wb + offs[20], *k1s = wb + offs[21], *k1c = wb + offs[22];
    const unsigned short *k2b = wb + offs[23], *k2s = wb + offs[24], *k2c = wb + offs[25];

    srt_detect<<<1, 64, 0, stream>>>((const unsigned int*)d_in[0], flag);
    srt_conv<<<1024, 256, 0, stream>>>(ct, wb, flag);
    srt_prep<<<512, 256, 0, stream>>>(h0s, s, bias0, bias1, b0ih, b0hh, b1ih, b1hh, seq);

    if (pipe_ok){
        unsigned short* xb   = (unsigned short*)dyn;
        unsigned short* gi0a = xb + xb_sz;
        unsigned short* gi0b = gi0a + slab_gi;
        unsigned short* haa  = gi0b + slab_gi;
        unsigned short* hab  = haa + slab_ha;
        unsigned short* gi1a = hab + slab_ha;
        unsigned short* gi1b = gi1a + slab_gi;

        srt_xconv<<<2048, 256, 0, stream>>>(d_in[0], xb, flag);

        PA a;
        a.xb = xb;
        a.w0ih = w0ih; a.w0hh = w0hh; a.b0hh = b0hh;
        a.w1ih = w1ih; a.w1hh = w1hh; a.b1hh = b1hh;
        a.bias0 = bias0; a.bias1 = bias1;
        a.h0s = h0s; a.h1s = s;
        a.gi0a = gi0a; a.gi0b = gi0b; a.haa = haa; a.hab = hab;
        a.gi1a = gi1a; a.gi1b = gi1b;
        for (int ph = 0; ph <= NCp + 2; ++ph){
            a.p = ph;
            srt_phase<<<256, 512, 0, stream>>>(a);
        }
    } else {
        srt_gru<<<128, 256, 0, stream>>>(d_in[0], w0ih, w0hh, b0ih, b0hh,
                                         w1ih, w1hh, b1ih, b1hh, s, flag, seq, hb);
    }

    srt_tail<<<512, 1024, 0, stream>>>(s,
        lwih0, lbih0, lbhh0, lwih0r, lbih0r, lbhh0r,
        lwih1, lbih1, lbhh1, lwih1r, lbih1r, lbhh1r,
        k1b, k1s, k1c, k2b, k2s, k2c, d_out, flag);
}